// Round 9
// baseline (452.084 us; speedup 1.0000x reference)
//
#include <hip/hip_runtime.h>
#include <hip/hip_bf16.h>

#define B_ 16
#define N_ 8192
#define C_ 512
#define H_ 8
#define HD_ 64
#define CH_ 64

// ws float layout:
//   [0, 512)          qfull (cls@Wq * scale)
//   [512, 4608)       qk[h][c]  (8 x 512)
//   [4608, 4736)      Linv[b][h]  (16 x 8)
//   [4736, 70272)     aa[b][h][c] unnormalized weighted sums (16 x 8 x 512)
//   [70272, 86656)    pp[half][b][o] partial pooled (2 x 16 x 512)
//   [86656, ...)      partials: per (b,chunk): { l[8], acc[8*512] } stride 4104
#define WS_QK   512
#define WS_LINV 4608
#define WS_AA   4736
#define WS_PP   70272
#define WS_PART 86656

// R8 probe counters (k_main code, 3-pass): VALUBusy 49%, hbm 27%, Occ 11%,
// VGPR 152. Diagnosis: latency-stall-bound at 2 blocks/CU (grid 512) and
// 2-3 waves/SIMD. R9 fix: CH=64 (1024 blocks) + depth-4 prefetch +
// launch_bounds(256,4) to pin VGPR<=128 -> 4 waves/SIMD, 16 waves/CU.

// ---------------- K1: qfull = cls @ Wq * HD^-0.5 ----------------
__global__ void k_qfull(const float* __restrict__ cls, const float* __restrict__ Wq,
                        float* __restrict__ ws) {
    __shared__ float red[256];
    int t = threadIdx.x;
    int o = blockIdx.x * 64 + (t & 63);
    int q = t >> 6;  // 0..3
    float p = 0.f;
#pragma unroll 16
    for (int c = q * 128; c < q * 128 + 128; ++c)
        p += cls[c] * Wq[c * C_ + o];
    red[t] = p;
    __syncthreads();
    if (t < 64) {
        float s = red[t] + red[t + 64] + red[t + 128] + red[t + 192];
        ws[o] = s * 0.125f;  // HD^-0.5 = 1/8
    }
}

// ---------------- K2: qk[h][c] = sum_d Wk[c, h*64+d] * qfull[h*64+d] ----------------
__global__ void k_qk(const float* __restrict__ Wk, float* __restrict__ ws) {
    __shared__ float wrow[8 * 520];  // 8 rows of Wk, padded stride
    __shared__ float qf[512];
    int t = threadIdx.x;
    int c0 = blockIdx.x * 8;
    int r = t >> 5;             // 8 rows, 32 threads each
    int col = (t & 31) * 16;    // 16 floats per thread
    const float4* src = (const float4*)(Wk + (size_t)(c0 + r) * C_ + col);
    float4* dst = (float4*)(&wrow[r * 520 + col]);
    dst[0] = src[0]; dst[1] = src[1]; dst[2] = src[2]; dst[3] = src[3];
    if (t < 128) ((float4*)qf)[t] = ((const float4*)ws)[t];
    __syncthreads();
    if (t < 64) {
        int h = t >> 3, cc = t & 7;
        const float* wr = &wrow[cc * 520 + h * 64];
        const float* qh = &qf[h * 64];
        float s = 0.f;
#pragma unroll
        for (int d = 0; d < 64; ++d) s += wr[d] * qh[d];
        ws[WS_QK + h * C_ + c0 + cc] = s;
    }
}

// ---------------- K3: main streaming pass over x ----------------
// Lane owns cols [4L,4L+4) and [256+4L,+4). Folded butterfly: lane ends with
// head f(lane)=4*b0+2*b1+b2; source lane for head h is bitrev3(h).
__global__ __launch_bounds__(256, 4) void k_main(const float* __restrict__ x,
                                                 const float* __restrict__ ws,
                                                 float* __restrict__ part, int CH) {
    int blk = blockIdx.x;
    int b = blk / CH, chunk = blk % CH;
    int lane = threadIdx.x & 63, wave = threadIdx.x >> 6;
    int rpb = N_ / CH;       // rows per block (128 at CH=64)
    int rpw = rpb >> 2;      // rows per wave (32)
    int n0 = chunk * rpb + wave * rpw;

    const float* qk = ws + WS_QK;
    float qr[8][8];
#pragma unroll
    for (int h = 0; h < 8; ++h) {
        float4 a = *(const float4*)(qk + h * C_ + 4 * lane);
        float4 bb = *(const float4*)(qk + h * C_ + 256 + 4 * lane);
        qr[h][0] = a.x;  qr[h][1] = a.y;  qr[h][2] = a.z;  qr[h][3] = a.w;
        qr[h][4] = bb.x; qr[h][5] = bb.y; qr[h][6] = bb.z; qr[h][7] = bb.w;
    }

    float acc[8][8];
#pragma unroll
    for (int h = 0; h < 8; ++h)
#pragma unroll
        for (int j = 0; j < 8; ++j) acc[h][j] = 0.f;
    float lsum = 0.f;

    const float* xp = x + ((size_t)b * N_ + n0) * C_;
    int lo = 4 * lane, hi = 256 + 4 * lane;

    auto row_body = [&](const float4& v0, const float4& v1) {
        float xv[8] = {v0.x, v0.y, v0.z, v0.w, v1.x, v1.y, v1.z, v1.w};
        float p[8];
#pragma unroll
        for (int h = 0; h < 8; ++h) {
            float s = xv[0] * qr[h][0];
#pragma unroll
            for (int j = 1; j < 8; ++j) s = fmaf(xv[j], qr[h][j], s);
            p[h] = s;
        }
        int b0 = lane & 1, b1 = lane & 2, b2 = lane & 4;
        float t4[4];
#pragma unroll
        for (int i = 0; i < 4; ++i) {
            float send = b0 ? p[i] : p[i + 4];
            float recv = __shfl_xor(send, 1, 64);
            t4[i] = (b0 ? p[i + 4] : p[i]) + recv;
        }
        float u2[2];
#pragma unroll
        for (int i = 0; i < 2; ++i) {
            float send = b1 ? t4[i] : t4[i + 2];
            float recv = __shfl_xor(send, 2, 64);
            u2[i] = (b1 ? t4[i + 2] : t4[i]) + recv;
        }
        float send = b2 ? u2[0] : u2[1];
        float recv = __shfl_xor(send, 4, 64);
        float v = (b2 ? u2[1] : u2[0]) + recv;
        v += __shfl_xor(v, 8, 64);
        v += __shfl_xor(v, 16, 64);
        v += __shfl_xor(v, 32, 64);
        float e = __expf(v);   // logits ~N(0,0.2): un-normalized softmax is safe
        lsum += e;
#pragma unroll
        for (int h = 0; h < 8; ++h) {
            int src = ((h & 4) >> 2) | (h & 2) | ((h & 1) << 2);
            float wf = __int_as_float(__builtin_amdgcn_readlane(__float_as_int(e), src));
#pragma unroll
            for (int j = 0; j < 8; ++j) acc[h][j] = fmaf(wf, xv[j], acc[h][j]);
        }
    };

    // prefetch depth 4 (8 KB in flight per wave; VGPR budget ~120 -> 4 waves/SIMD)
    float4 R[4][2];
#pragma unroll
    for (int k = 0; k < 4; ++k) {
        R[k][0] = *(const float4*)(xp + (size_t)k * C_ + lo);
        R[k][1] = *(const float4*)(xp + (size_t)k * C_ + hi);
    }
#pragma unroll 1
    for (int i = 0; i < rpw; i += 4) {
#pragma unroll
        for (int k = 0; k < 4; ++k) {
            float4 v0 = R[k][0], v1 = R[k][1];
            int nf = i + k + 4; nf = nf < rpw ? nf : rpw - 1;  // clamped prefetch
            R[k][0] = *(const float4*)(xp + (size_t)nf * C_ + lo);
            R[k][1] = *(const float4*)(xp + (size_t)nf * C_ + hi);
            row_body(v0, v1);
        }
    }

    // per-wave l values (uniform), then block-combine in LDS
    float lw[8];
#pragma unroll
    for (int h = 0; h < 8; ++h) {
        int src = ((h & 4) >> 2) | (h & 2) | ((h & 1) << 2);
        lw[h] = __int_as_float(__builtin_amdgcn_readlane(__float_as_int(lsum), src));
    }

    __shared__ float sacc[8 * 512];
    __shared__ float sl[8];
    for (int w = 0; w < 4; ++w) {
        if (wave == w) {
#pragma unroll
            for (int h = 0; h < 8; ++h) {
                float4 vlo = {acc[h][0], acc[h][1], acc[h][2], acc[h][3]};
                float4 vhi = {acc[h][4], acc[h][5], acc[h][6], acc[h][7]};
                float4* d0 = (float4*)&sacc[h * C_ + lo];
                float4* d1 = (float4*)&sacc[h * C_ + hi];
                if (w == 0) { d0[0] = vlo; d1[0] = vhi; }
                else {
                    float4 a0 = d0[0], a1 = d1[0];
                    a0.x += vlo.x; a0.y += vlo.y; a0.z += vlo.z; a0.w += vlo.w;
                    a1.x += vhi.x; a1.y += vhi.y; a1.z += vhi.z; a1.w += vhi.w;
                    d0[0] = a0; d1[0] = a1;
                }
            }
            if (lane == 0) {
#pragma unroll
                for (int h = 0; h < 8; ++h) {
                    if (w == 0) sl[h] = lw[h]; else sl[h] += lw[h];
                }
            }
        }
        __syncthreads();
    }

    float* pb = part + (size_t)blk * 4104;
    if (threadIdx.x < 8) pb[threadIdx.x] = sl[threadIdx.x];
    float* pa = pb + 8;
    for (int k = threadIdx.x; k < 4096; k += 256) pa[k] = sacc[k];
}

// ---------------- K4: reduce partials -> aa (unnormalized), Linv ----------------
__global__ void k_reduce(const float* __restrict__ part, float* __restrict__ ws, int CH) {
    int b = blockIdx.x >> 4, cc = blockIdx.x & 15, t = threadIdx.x;
    int h = t >> 5, c = cc * 32 + (t & 31);
    const float* pb = part + (size_t)b * CH * 4104;
    float s = 0.f;
#pragma unroll 8
    for (int p = 0; p < CH; ++p) s += pb[(size_t)p * 4104 + 8 + h * C_ + c];
    ws[WS_AA + b * 4096 + h * C_ + c] = s;
    if (cc == 0 && t < 8) {
        float ls = 0.f;
#pragma unroll 8
        for (int p = 0; p < CH; ++p) ls += pb[(size_t)p * 4104 + t];
        ws[WS_LINV + b * 8 + t] = 1.f / ls;
    }
}

// ---------------- K5: pooled (c-split halves) = Linv * aa @ Wv ----------------
__global__ void k_proj1(const float* __restrict__ ws, const float* __restrict__ Wv,
                        float* __restrict__ pp) {
    int gid = blockIdx.x * 256 + threadIdx.x;  // [0, 16384)
    int half = gid >> 13;
    int r = gid & 8191;
    int b = r >> 9, o = r & 511, h = o >> 6;
    const float* aa = ws + WS_AA + b * 4096 + h * C_;
    float Li = ws[WS_LINV + b * 8 + h];
    int c0 = half * 256;
    float s = 0.f;
#pragma unroll 16
    for (int c = 0; c < 256; ++c)
        s = fmaf(aa[c0 + c], Wv[(size_t)(c0 + c) * C_ + o], s);
    pp[half * 8192 + r] = s * Li;
}

// ---------------- K6: out = pooled @ Wp + bp ----------------
__global__ void k_proj2(const float* __restrict__ ws, const float* __restrict__ Wp,
                        const float* __restrict__ bp, float* __restrict__ out) {
    int gid = blockIdx.x * 256 + threadIdx.x;  // [0, 8192)
    int b = gid >> 9, o = gid & 511;
    const float* pp = ws + WS_PP + b * 512;
    float s = bp[o];
#pragma unroll 16
    for (int c = 0; c < 512; ++c) {
        float pc = pp[c] + pp[8192 + c];
        s = fmaf(pc, Wp[(size_t)c * C_ + o], s);
    }
    out[(size_t)b * C_ + o] = s;
}

extern "C" void kernel_launch(void* const* d_in, const int* in_sizes, int n_in,
                              void* d_out, int out_size, void* d_ws, size_t ws_size,
                              hipStream_t stream) {
    const float* x   = (const float*)d_in[0];
    const float* cls = (const float*)d_in[1];
    const float* Wq  = (const float*)d_in[2];
    const float* Wk  = (const float*)d_in[3];
    const float* Wv  = (const float*)d_in[4];
    const float* Wp  = (const float*)d_in[5];
    const float* bp  = (const float*)d_in[6];
    float* out = (float*)d_out;
    float* ws  = (float*)d_ws;

    int CH = CH_;
    while (CH > 1 && (size_t)(WS_PART + (size_t)B_ * CH * 4104) * 4 > ws_size) CH >>= 1;

    k_qfull<<<8, 256, 0, stream>>>(cls, Wq, ws);
    k_qk<<<64, 256, 0, stream>>>(Wk, ws);
    k_main<<<B_ * CH, 256, 0, stream>>>(x, ws, ws + WS_PART, CH);
    k_reduce<<<B_ * 16, 256, 0, stream>>>(ws + WS_PART, ws, CH);
    k_proj1<<<64, 256, 0, stream>>>(ws, Wv, ws + WS_PP);
    k_proj2<<<32, 256, 0, stream>>>(ws, Wp, bp, out);
}

// Round 10
// 125.770 us; speedup vs baseline: 3.5945x; 3.5945x over previous
//
#include <hip/hip_runtime.h>
#include <hip/hip_bf16.h>

#define B_ 16
#define N_ 8192
#define C_ 512
#define H_ 8
#define HD_ 64
#define CH_ 64

// ws float layout:
//   [0, 512)          qfull (cls@Wq * scale)
//   [512, 4608)       qk[h][c]  (8 x 512)
//   [4608, 4736)      Linv[b][h]  (16 x 8)
//   [4736, 70272)     aa[b][h][c] unnormalized weighted sums (16 x 8 x 512)
//   [70272, 86656)    pp[half][b][o] partial pooled (2 x 16 x 512)
//   [86656, ...)      partials: per (b,chunk): { l[8], acc[8*512] } stride 4104
#define WS_QK   512
#define WS_LINV 4608
#define WS_AA   4736
#define WS_PP   70272
#define WS_PART 86656

// Measured history for k_main (the 256MB streaming pass):
//  R8 probe: VGPR 152, VALUBusy 49%, hbm 27%, Occ 11%, ~63us/pass L3-warm
//            -> latency-bound, grid-limited (CH=32 -> 512 blocks = 2/CU).
//  R9: __launch_bounds__(256,4) forced VGPR=64 -> massive spill (FETCH+256MB,
//      WRITE+856MB, VALUBusy 7%) -> 422us. NEVER force min-occupancy here.
//  R10: CH=64 (1024 blocks) + depth-4 prefetch (VGPR ~120) -> 3-4 waves/SIMD.

// ---------------- K1: qfull = cls @ Wq * HD^-0.5 ----------------
__global__ void k_qfull(const float* __restrict__ cls, const float* __restrict__ Wq,
                        float* __restrict__ ws) {
    __shared__ float red[256];
    int t = threadIdx.x;
    int o = blockIdx.x * 64 + (t & 63);
    int q = t >> 6;  // 0..3
    float p = 0.f;
#pragma unroll 16
    for (int c = q * 128; c < q * 128 + 128; ++c)
        p += cls[c] * Wq[c * C_ + o];
    red[t] = p;
    __syncthreads();
    if (t < 64) {
        float s = red[t] + red[t + 64] + red[t + 128] + red[t + 192];
        ws[o] = s * 0.125f;  // HD^-0.5 = 1/8
    }
}

// ---------------- K2: qk[h][c] = sum_d Wk[c, h*64+d] * qfull[h*64+d] ----------------
__global__ void k_qk(const float* __restrict__ Wk, float* __restrict__ ws) {
    __shared__ float wrow[8 * 520];  // 8 rows of Wk, padded stride
    __shared__ float qf[512];
    int t = threadIdx.x;
    int c0 = blockIdx.x * 8;
    int r = t >> 5;             // 8 rows, 32 threads each
    int col = (t & 31) * 16;    // 16 floats per thread
    const float4* src = (const float4*)(Wk + (size_t)(c0 + r) * C_ + col);
    float4* dst = (float4*)(&wrow[r * 520 + col]);
    dst[0] = src[0]; dst[1] = src[1]; dst[2] = src[2]; dst[3] = src[3];
    if (t < 128) ((float4*)qf)[t] = ((const float4*)ws)[t];
    __syncthreads();
    if (t < 64) {
        int h = t >> 3, cc = t & 7;
        const float* wr = &wrow[cc * 520 + h * 64];
        const float* qh = &qf[h * 64];
        float s = 0.f;
#pragma unroll
        for (int d = 0; d < 64; ++d) s += wr[d] * qh[d];
        ws[WS_QK + h * C_ + c0 + cc] = s;
    }
}

// ---------------- K3: main streaming pass over x ----------------
// Lane owns cols [4L,4L+4) and [256+4L,+4). Folded butterfly: lane ends with
// head f(lane)=4*b0+2*b1+b2; source lane for head h is bitrev3(h).
__global__ __launch_bounds__(256) void k_main(const float* __restrict__ x,
                                              const float* __restrict__ ws,
                                              float* __restrict__ part, int CH) {
    int blk = blockIdx.x;
    int b = blk / CH, chunk = blk % CH;
    int lane = threadIdx.x & 63, wave = threadIdx.x >> 6;
    int rpb = N_ / CH;       // rows per block (128 at CH=64)
    int rpw = rpb >> 2;      // rows per wave (32)
    int n0 = chunk * rpb + wave * rpw;

    const float* qk = ws + WS_QK;
    float qr[8][8];
#pragma unroll
    for (int h = 0; h < 8; ++h) {
        float4 a = *(const float4*)(qk + h * C_ + 4 * lane);
        float4 bb = *(const float4*)(qk + h * C_ + 256 + 4 * lane);
        qr[h][0] = a.x;  qr[h][1] = a.y;  qr[h][2] = a.z;  qr[h][3] = a.w;
        qr[h][4] = bb.x; qr[h][5] = bb.y; qr[h][6] = bb.z; qr[h][7] = bb.w;
    }

    float acc[8][8];
#pragma unroll
    for (int h = 0; h < 8; ++h)
#pragma unroll
        for (int j = 0; j < 8; ++j) acc[h][j] = 0.f;
    float lsum = 0.f;

    const float* xp = x + ((size_t)b * N_ + n0) * C_;
    int lo = 4 * lane, hi = 256 + 4 * lane;

    auto row_body = [&](const float4& v0, const float4& v1) {
        float xv[8] = {v0.x, v0.y, v0.z, v0.w, v1.x, v1.y, v1.z, v1.w};
        float p[8];
#pragma unroll
        for (int h = 0; h < 8; ++h) {
            float s = xv[0] * qr[h][0];
#pragma unroll
            for (int j = 1; j < 8; ++j) s = fmaf(xv[j], qr[h][j], s);
            p[h] = s;
        }
        int b0 = lane & 1, b1 = lane & 2, b2 = lane & 4;
        float t4[4];
#pragma unroll
        for (int i = 0; i < 4; ++i) {
            float send = b0 ? p[i] : p[i + 4];
            float recv = __shfl_xor(send, 1, 64);
            t4[i] = (b0 ? p[i + 4] : p[i]) + recv;
        }
        float u2[2];
#pragma unroll
        for (int i = 0; i < 2; ++i) {
            float send = b1 ? t4[i] : t4[i + 2];
            float recv = __shfl_xor(send, 2, 64);
            u2[i] = (b1 ? t4[i + 2] : t4[i]) + recv;
        }
        float send = b2 ? u2[0] : u2[1];
        float recv = __shfl_xor(send, 4, 64);
        float v = (b2 ? u2[1] : u2[0]) + recv;
        v += __shfl_xor(v, 8, 64);
        v += __shfl_xor(v, 16, 64);
        v += __shfl_xor(v, 32, 64);
        float e = __expf(v);   // logits ~N(0,0.2): un-normalized softmax is safe
        lsum += e;
#pragma unroll
        for (int h = 0; h < 8; ++h) {
            int src = ((h & 4) >> 2) | (h & 2) | ((h & 1) << 2);
            float wf = __int_as_float(__builtin_amdgcn_readlane(__float_as_int(e), src));
#pragma unroll
            for (int j = 0; j < 8; ++j) acc[h][j] = fmaf(wf, xv[j], acc[h][j]);
        }
    };

    // prefetch depth 4 (8 KB in flight/wave; VGPR ~120 -> 3-4 waves/SIMD)
    float4 R[4][2];
#pragma unroll
    for (int k = 0; k < 4; ++k) {
        R[k][0] = *(const float4*)(xp + (size_t)k * C_ + lo);
        R[k][1] = *(const float4*)(xp + (size_t)k * C_ + hi);
    }
#pragma unroll 1
    for (int i = 0; i < rpw; i += 4) {
#pragma unroll
        for (int k = 0; k < 4; ++k) {
            float4 v0 = R[k][0], v1 = R[k][1];
            int nf = i + k + 4; nf = nf < rpw ? nf : rpw - 1;  // clamped prefetch
            R[k][0] = *(const float4*)(xp + (size_t)nf * C_ + lo);
            R[k][1] = *(const float4*)(xp + (size_t)nf * C_ + hi);
            row_body(v0, v1);
        }
    }

    // per-wave l values (uniform), then block-combine in LDS
    float lw[8];
#pragma unroll
    for (int h = 0; h < 8; ++h) {
        int src = ((h & 4) >> 2) | (h & 2) | ((h & 1) << 2);
        lw[h] = __int_as_float(__builtin_amdgcn_readlane(__float_as_int(lsum), src));
    }

    __shared__ float sacc[8 * 512];
    __shared__ float sl[8];
    for (int w = 0; w < 4; ++w) {
        if (wave == w) {
#pragma unroll
            for (int h = 0; h < 8; ++h) {
                float4 vlo = {acc[h][0], acc[h][1], acc[h][2], acc[h][3]};
                float4 vhi = {acc[h][4], acc[h][5], acc[h][6], acc[h][7]};
                float4* d0 = (float4*)&sacc[h * C_ + lo];
                float4* d1 = (float4*)&sacc[h * C_ + hi];
                if (w == 0) { d0[0] = vlo; d1[0] = vhi; }
                else {
                    float4 a0 = d0[0], a1 = d1[0];
                    a0.x += vlo.x; a0.y += vlo.y; a0.z += vlo.z; a0.w += vlo.w;
                    a1.x += vhi.x; a1.y += vhi.y; a1.z += vhi.z; a1.w += vhi.w;
                    d0[0] = a0; d1[0] = a1;
                }
            }
            if (lane == 0) {
#pragma unroll
                for (int h = 0; h < 8; ++h) {
                    if (w == 0) sl[h] = lw[h]; else sl[h] += lw[h];
                }
            }
        }
        __syncthreads();
    }

    float* pb = part + (size_t)blk * 4104;
    if (threadIdx.x < 8) pb[threadIdx.x] = sl[threadIdx.x];
    float* pa = pb + 8;
#pragma unroll 4
    for (int k = threadIdx.x; k < 4096; k += 256) pa[k] = sacc[k];
}

// ---------------- K4: reduce partials -> aa (unnormalized), Linv ----------------
__global__ void k_reduce(const float* __restrict__ part, float* __restrict__ ws, int CH) {
    int b = blockIdx.x >> 4, cc = blockIdx.x & 15, t = threadIdx.x;
    int h = t >> 5, c = cc * 32 + (t & 31);
    const float* pb = part + (size_t)b * CH * 4104;
    float s = 0.f;
#pragma unroll 8
    for (int p = 0; p < CH; ++p) s += pb[(size_t)p * 4104 + 8 + h * C_ + c];
    ws[WS_AA + b * 4096 + h * C_ + c] = s;
    if (cc == 0 && t < 8) {
        float ls = 0.f;
#pragma unroll 8
        for (int p = 0; p < CH; ++p) ls += pb[(size_t)p * 4104 + t];
        ws[WS_LINV + b * 8 + t] = 1.f / ls;
    }
}

// ---------------- K5: pooled (c-split halves) = Linv * aa @ Wv ----------------
__global__ void k_proj1(const float* __restrict__ ws, const float* __restrict__ Wv,
                        float* __restrict__ pp) {
    int gid = blockIdx.x * 256 + threadIdx.x;  // [0, 16384)
    int half = gid >> 13;
    int r = gid & 8191;
    int b = r >> 9, o = r & 511, h = o >> 6;
    const float* aa = ws + WS_AA + b * 4096 + h * C_;
    float Li = ws[WS_LINV + b * 8 + h];
    int c0 = half * 256;
    float s = 0.f;
#pragma unroll 16
    for (int c = 0; c < 256; ++c)
        s = fmaf(aa[c0 + c], Wv[(size_t)(c0 + c) * C_ + o], s);
    pp[half * 8192 + r] = s * Li;
}

// ---------------- K6: out = pooled @ Wp + bp ----------------
__global__ void k_proj2(const float* __restrict__ ws, const float* __restrict__ Wp,
                        const float* __restrict__ bp, float* __restrict__ out) {
    int gid = blockIdx.x * 256 + threadIdx.x;  // [0, 8192)
    int b = gid >> 9, o = gid & 511;
    const float* pp = ws + WS_PP + b * 512;
    float s = bp[o];
#pragma unroll 16
    for (int c = 0; c < 512; ++c) {
        float pc = pp[c] + pp[8192 + c];
        s = fmaf(pc, Wp[(size_t)c * C_ + o], s);
    }
    out[(size_t)b * C_ + o] = s;
}

extern "C" void kernel_launch(void* const* d_in, const int* in_sizes, int n_in,
                              void* d_out, int out_size, void* d_ws, size_t ws_size,
                              hipStream_t stream) {
    const float* x   = (const float*)d_in[0];
    const float* cls = (const float*)d_in[1];
    const float* Wq  = (const float*)d_in[2];
    const float* Wk  = (const float*)d_in[3];
    const float* Wv  = (const float*)d_in[4];
    const float* Wp  = (const float*)d_in[5];
    const float* bp  = (const float*)d_in[6];
    float* out = (float*)d_out;
    float* ws  = (float*)d_ws;

    int CH = CH_;
    while (CH > 1 && (size_t)(WS_PART + (size_t)B_ * CH * 4104) * 4 > ws_size) CH >>= 1;

    k_qfull<<<8, 256, 0, stream>>>(cls, Wq, ws);
    k_qk<<<64, 256, 0, stream>>>(Wk, ws);
    k_main<<<B_ * CH, 256, 0, stream>>>(x, ws, ws + WS_PART, CH);
    k_reduce<<<B_ * 16, 256, 0, stream>>>(ws + WS_PART, ws, CH);
    k_proj1<<<64, 256, 0, stream>>>(ws, Wv, ws + WS_PP);
    k_proj2<<<32, 256, 0, stream>>>(ws, Wp, bp, out);
}

// Round 11
// 122.265 us; speedup vs baseline: 3.6976x; 1.0287x over previous
//
#include <hip/hip_runtime.h>
#include <hip/hip_bf16.h>

#define B_ 16
#define N_ 8192
#define C_ 512
#define H_ 8
#define CH_ 64
#define NT_ 16   // tiles per block (128 rows / 8 rows-per-tile)

// ws float layout:
//   [0, 512)          qfull (cls@Wq * scale)
//   [512, 4608)       qk[h][c]  (8 x 512)
//   [4608, 4736)      Linv[b][h]  (16 x 8)
//   [4736, 70272)     aa[b][h][c] unnormalized weighted sums (16 x 8 x 512)
//   [70272, 86656)    pp[half][b][o] partial pooled (2 x 16 x 512)
//   [86656, ...)      partials: per (b,chunk): { l[8], acc[8*512] } stride 4104
#define WS_QK   512
#define WS_LINV 4608
#define WS_AA   4736
#define WS_PP   70272
#define WS_PART 86656

// k_main history: R8 probe showed consumption capped ~4.1TB/s, VALUBusy 49%,
// with occupancy (R10) and prefetch-depth (R3/R7) both falsified as levers.
// Little's law at ~2KB/wave in flight reproduces the cap exactly: the compiler
// sinks register prefetch loads to their use. R11: global_load_lds DMA
// (cannot be sunk; no dest reg) + counted vmcnt(4), zero in-loop barriers.

#if defined(__has_builtin)
#if __has_builtin(__builtin_amdgcn_global_load_lds)
#define HAVE_GLD 1
#endif
#endif

#ifdef HAVE_GLD
// g: per-lane global address (16B/lane). l: wave-uniform LDS base; HW adds lane*16.
__device__ __forceinline__ void dma16(const float* g, float* l) {
    __builtin_amdgcn_global_load_lds(
        (const __attribute__((address_space(1))) unsigned int*)g,
        (__attribute__((address_space(3))) unsigned int*)l, 16, 0, 0);
}
#else
__device__ __forceinline__ void dma16(const float* g, float* l) {
    *(float4*)(l + 4 * (threadIdx.x & 63)) = *(const float4*)g;
}
#endif

// ---------------- K1: qfull = cls @ Wq * HD^-0.5 ----------------
__global__ void k_qfull(const float* __restrict__ cls, const float* __restrict__ Wq,
                        float* __restrict__ ws) {
    __shared__ float red[256];
    int t = threadIdx.x;
    int o = blockIdx.x * 64 + (t & 63);
    int q = t >> 6;  // 0..3
    float p = 0.f;
#pragma unroll 16
    for (int c = q * 128; c < q * 128 + 128; ++c)
        p += cls[c] * Wq[c * C_ + o];
    red[t] = p;
    __syncthreads();
    if (t < 64) {
        float s = red[t] + red[t + 64] + red[t + 128] + red[t + 192];
        ws[o] = s * 0.125f;  // HD^-0.5 = 1/8
    }
}

// ---------------- K2: qk[h][c] = sum_d Wk[c, h*64+d] * qfull[h*64+d] ----------------
__global__ void k_qk(const float* __restrict__ Wk, float* __restrict__ ws) {
    __shared__ float wrow[8 * 520];  // 8 rows of Wk, padded stride
    __shared__ float qf[512];
    int t = threadIdx.x;
    int c0 = blockIdx.x * 8;
    int r = t >> 5;             // 8 rows, 32 threads each
    int col = (t & 31) * 16;    // 16 floats per thread
    const float4* src = (const float4*)(Wk + (size_t)(c0 + r) * C_ + col);
    float4* dst = (float4*)(&wrow[r * 520 + col]);
    dst[0] = src[0]; dst[1] = src[1]; dst[2] = src[2]; dst[3] = src[3];
    if (t < 128) ((float4*)qf)[t] = ((const float4*)ws)[t];
    __syncthreads();
    if (t < 64) {
        int h = t >> 3, cc = t & 7;
        const float* wr = &wrow[cc * 520 + h * 64];
        const float* qh = &qf[h * 64];
        float s = 0.f;
#pragma unroll
        for (int d = 0; d < 64; ++d) s += wr[d] * qh[d];
        ws[WS_QK + h * C_ + c0 + cc] = s;
    }
}

// ---------------- K3: main streaming pass over x (DMA-FIFO, round 11) ----------------
// Per block (CH=64): 128 rows, 16 tiles x 8 rows. Wave w owns rows {2w,2w+1}
// of every tile, staged by ITS OWN global_load_lds into a private 8KB LDS
// double-buffer. Counted vmcnt(4) per tile; no in-loop __syncthreads.
// Folded butterfly row math identical to R7 (verified).
__global__ __launch_bounds__(256) void k_main(const float* __restrict__ x,
                                              const float* __restrict__ ws,
                                              float* __restrict__ part, int CH) {
    __shared__ float smem[4][2][1024];   // wave-private [w][buf][2 rows]; 32 KB
    __shared__ float sl[8];

    int blk = blockIdx.x;
    int b = blk / CH, chunk = blk % CH;
    int lane = threadIdx.x & 63, wave = threadIdx.x >> 6;
    int rpb = N_ / CH;            // 128
    int n0 = chunk * rpb;
    const float* xp = x + ((size_t)b * N_ + n0) * C_;
    const float* gw = xp + (size_t)(2 * wave) * C_;   // this wave's rows in tile 0

    const float* qk = ws + WS_QK;
    int lo = 4 * lane, hi = 256 + 4 * lane;
    float qr[8][8];
#pragma unroll
    for (int h = 0; h < 8; ++h) {
        float4 a = *(const float4*)(qk + h * C_ + lo);
        float4 bb = *(const float4*)(qk + h * C_ + hi);
        qr[h][0] = a.x;  qr[h][1] = a.y;  qr[h][2] = a.z;  qr[h][3] = a.w;
        qr[h][4] = bb.x; qr[h][5] = bb.y; qr[h][6] = bb.z; qr[h][7] = bb.w;
    }

    float acc[8][8];
#pragma unroll
    for (int h = 0; h < 8; ++h)
#pragma unroll
        for (int j = 0; j < 8; ++j) acc[h][j] = 0.f;
    float lsum = 0.f;

    auto row_body = [&](const float4& v0, const float4& v1) {
        float xv[8] = {v0.x, v0.y, v0.z, v0.w, v1.x, v1.y, v1.z, v1.w};
        float p[8];
#pragma unroll
        for (int h = 0; h < 8; ++h) {
            float s = xv[0] * qr[h][0];
#pragma unroll
            for (int j = 1; j < 8; ++j) s = fmaf(xv[j], qr[h][j], s);
            p[h] = s;
        }
        int b0 = lane & 1, b1 = lane & 2, b2 = lane & 4;
        float t4[4];
#pragma unroll
        for (int i = 0; i < 4; ++i) {
            float send = b0 ? p[i] : p[i + 4];
            float recv = __shfl_xor(send, 1, 64);
            t4[i] = (b0 ? p[i + 4] : p[i]) + recv;
        }
        float u2[2];
#pragma unroll
        for (int i = 0; i < 2; ++i) {
            float send = b1 ? t4[i] : t4[i + 2];
            float recv = __shfl_xor(send, 2, 64);
            u2[i] = (b1 ? t4[i + 2] : t4[i]) + recv;
        }
        float send = b2 ? u2[0] : u2[1];
        float recv = __shfl_xor(send, 4, 64);
        float v = (b2 ? u2[1] : u2[0]) + recv;
        v += __shfl_xor(v, 8, 64);
        v += __shfl_xor(v, 16, 64);
        v += __shfl_xor(v, 32, 64);
        float e = __expf(v);   // logits ~N(0,0.2): un-normalized softmax is safe
        lsum += e;
#pragma unroll
        for (int h = 0; h < 8; ++h) {
            int src = ((h & 4) >> 2) | (h & 2) | ((h & 1) << 2);
            float wf = __int_as_float(__builtin_amdgcn_readlane(__float_as_int(e), src));
#pragma unroll
            for (int j = 0; j < 8; ++j) acc[h][j] = fmaf(wf, xv[j], acc[h][j]);
        }
    };

    float* Lb[2] = {&smem[wave][0][0], &smem[wave][1][0]};

    // prologue: stage tile 0 (4 x 1KB DMA, fire-and-forget)
#pragma unroll
    for (int k = 0; k < 4; ++k)
        dma16(gw + k * 256 + lo, Lb[0] + k * 256);

#pragma unroll 1
    for (int T = 0; T < NT_; ++T) {
        float* cur = Lb[T & 1];
        float* nxt = Lb[(T & 1) ^ 1];
        if (T + 1 < NT_) {
            const float* gn = gw + (size_t)(T + 1) * 8 * C_;
#pragma unroll
            for (int k = 0; k < 4; ++k)
                dma16(gn + k * 256 + lo, nxt + k * 256);
            asm volatile("s_waitcnt vmcnt(4)" ::: "memory");  // tile T landed
        } else {
            asm volatile("s_waitcnt vmcnt(0)" ::: "memory");  // final tile
        }
#pragma unroll
        for (int r = 0; r < 2; ++r) {
            float4 v0 = *(const float4*)(cur + r * 512 + lo);
            float4 v1 = *(const float4*)(cur + r * 512 + hi);
            row_body(v0, v1);
        }
    }

    // per-wave l values (uniform)
    float lw[8];
#pragma unroll
    for (int h = 0; h < 8; ++h) {
        int src = ((h & 4) >> 2) | (h & 2) | ((h & 1) << 2);
        lw[h] = __int_as_float(__builtin_amdgcn_readlane(__float_as_int(lsum), src));
    }

    __syncthreads();   // all streaming reads done; smem now reusable as sacc
    float* sacc = &smem[0][0][0];   // 8*512 floats = 16 KB
    for (int w = 0; w < 4; ++w) {
        if (wave == w) {
#pragma unroll
            for (int h = 0; h < 8; ++h) {
                float4 vlo = {acc[h][0], acc[h][1], acc[h][2], acc[h][3]};
                float4 vhi = {acc[h][4], acc[h][5], acc[h][6], acc[h][7]};
                float4* d0 = (float4*)&sacc[h * C_ + lo];
                float4* d1 = (float4*)&sacc[h * C_ + hi];
                if (w == 0) { d0[0] = vlo; d1[0] = vhi; }
                else {
                    float4 a0 = d0[0], a1 = d1[0];
                    a0.x += vlo.x; a0.y += vlo.y; a0.z += vlo.z; a0.w += vlo.w;
                    a1.x += vhi.x; a1.y += vhi.y; a1.z += vhi.z; a1.w += vhi.w;
                    d0[0] = a0; d1[0] = a1;
                }
            }
            if (lane == 0) {
#pragma unroll
                for (int h = 0; h < 8; ++h) {
                    if (w == 0) sl[h] = lw[h]; else sl[h] += lw[h];
                }
            }
        }
        __syncthreads();
    }

    float* pb = part + (size_t)blk * 4104;
    if (threadIdx.x < 8) pb[threadIdx.x] = sl[threadIdx.x];
    float* pa = pb + 8;
#pragma unroll 4
    for (int k = threadIdx.x; k < 4096; k += 256) pa[k] = sacc[k];
}

// ---------------- K4: reduce partials -> aa (unnormalized), Linv ----------------
__global__ void k_reduce(const float* __restrict__ part, float* __restrict__ ws, int CH) {
    int b = blockIdx.x >> 4, cc = blockIdx.x & 15, t = threadIdx.x;
    int h = t >> 5, c = cc * 32 + (t & 31);
    const float* pb = part + (size_t)b * CH * 4104;
    float s = 0.f;
#pragma unroll 8
    for (int p = 0; p < CH; ++p) s += pb[(size_t)p * 4104 + 8 + h * C_ + c];
    ws[WS_AA + b * 4096 + h * C_ + c] = s;
    if (cc == 0 && t < 8) {
        float ls = 0.f;
#pragma unroll 8
        for (int p = 0; p < CH; ++p) ls += pb[(size_t)p * 4104 + t];
        ws[WS_LINV + b * 8 + t] = 1.f / ls;
    }
}

// ---------------- K5: pooled (c-split halves) = Linv * aa @ Wv ----------------
__global__ void k_proj1(const float* __restrict__ ws, const float* __restrict__ Wv,
                        float* __restrict__ pp) {
    int gid = blockIdx.x * 256 + threadIdx.x;  // [0, 16384)
    int half = gid >> 13;
    int r = gid & 8191;
    int b = r >> 9, o = r & 511, h = o >> 6;
    const float* aa = ws + WS_AA + b * 4096 + h * C_;
    float Li = ws[WS_LINV + b * 8 + h];
    int c0 = half * 256;
    float s = 0.f;
#pragma unroll 16
    for (int c = 0; c < 256; ++c)
        s = fmaf(aa[c0 + c], Wv[(size_t)(c0 + c) * C_ + o], s);
    pp[half * 8192 + r] = s * Li;
}

// ---------------- K6: out = pooled @ Wp + bp ----------------
__global__ void k_proj2(const float* __restrict__ ws, const float* __restrict__ Wp,
                        const float* __restrict__ bp, float* __restrict__ out) {
    int gid = blockIdx.x * 256 + threadIdx.x;  // [0, 8192)
    int b = gid >> 9, o = gid & 511;
    const float* pp = ws + WS_PP + b * 512;
    float s = bp[o];
#pragma unroll 16
    for (int c = 0; c < 512; ++c) {
        float pc = pp[c] + pp[8192 + c];
        s = fmaf(pc, Wp[(size_t)c * C_ + o], s);
    }
    out[(size_t)b * C_ + o] = s;
}

extern "C" void kernel_launch(void* const* d_in, const int* in_sizes, int n_in,
                              void* d_out, int out_size, void* d_ws, size_t ws_size,
                              hipStream_t stream) {
    const float* x   = (const float*)d_in[0];
    const float* cls = (const float*)d_in[1];
    const float* Wq  = (const float*)d_in[2];
    const float* Wk  = (const float*)d_in[3];
    const float* Wv  = (const float*)d_in[4];
    const float* Wp  = (const float*)d_in[5];
    const float* bp  = (const float*)d_in[6];
    float* out = (float*)d_out;
    float* ws  = (float*)d_ws;

    int CH = CH_;
    while (CH > 1 && (size_t)(WS_PART + (size_t)B_ * CH * 4104) * 4 > ws_size) CH >>= 1;

    k_qfull<<<8, 256, 0, stream>>>(cls, Wq, ws);
    k_qk<<<64, 256, 0, stream>>>(Wk, ws);
    k_main<<<B_ * CH, 256, 0, stream>>>(x, ws, ws + WS_PART, CH);
    k_reduce<<<B_ * 16, 256, 0, stream>>>(ws + WS_PART, ws, CH);
    k_proj1<<<64, 256, 0, stream>>>(ws, Wv, ws + WS_PP);
    k_proj2<<<32, 256, 0, stream>>>(ws, Wp, bp, out);
}

// Round 12
// 104.740 us; speedup vs baseline: 4.3162x; 1.1673x over previous
//
#include <hip/hip_runtime.h>
#include <hip/hip_bf16.h>

#define B_ 16
#define N_ 8192
#define C_ 512
#define H_ 8
#define CH_ 32
#define NT_ 32   // tiles per block (256 rows / 8 rows-per-tile)

// ws float layout (no partials round-trip anymore):
//   [512, 4608)       qk[h][c]  (8 x 512)
//   [4608, 4736)      l[b][h] atomic sums (16 x 8)
//   [4736, 70272)     aa[b][h][c] atomic-accumulated weighted sums (16 x 8 x 512)
//   [70272, 86656)    pp[half][b][o] partial pooled (2 x 16 x 512)
#define WS_QK   512
#define WS_L    4608
#define WS_AA   4736
#define WS_PP   70272

// History: R8 probe: k_main consumption-capped ~4.1TB/s (VALU 49%, ~60us incl
// cold HBM; ideal ~50). R7->R11: the OTHER ~60us is 5 serial small dispatches
// + 33MB partials round-trip. R12: fuse prep, kill k_reduce via fp32 atomics.

#if defined(__has_builtin)
#if __has_builtin(__builtin_amdgcn_global_load_lds)
#define HAVE_GLD 1
#endif
#endif

#ifdef HAVE_GLD
__device__ __forceinline__ void dma16(const float* g, float* l) {
    __builtin_amdgcn_global_load_lds(
        (const __attribute__((address_space(1))) unsigned int*)g,
        (__attribute__((address_space(3))) unsigned int*)l, 16, 0, 0);
}
#else
__device__ __forceinline__ void dma16(const float* g, float* l) {
    *(float4*)(l + 4 * (threadIdx.x & 63)) = *(const float4*)g;
}
#endif

// ---------------- K1: fused prep ----------------
// Block (h = blk>>3, cc = blk&7): recompute qfull[h*64..+64) from cls@Wq,
// then qk[h][cc*64..+64). Also zero aa (1024 floats/block) and l (block 0).
__global__ void k_prep(const float* __restrict__ cls, const float* __restrict__ Wq,
                       const float* __restrict__ Wk, float* __restrict__ ws) {
    __shared__ float red[256];
    __shared__ float qf[64];
    int t = threadIdx.x;
    int h = blockIdx.x >> 3, cc = blockIdx.x & 7;

    // zero the atomic accumulators (aa: 64 blocks x 1024 floats = 65536)
    {
        float4 z = {0.f, 0.f, 0.f, 0.f};
        *(float4*)(ws + WS_AA + blockIdx.x * 1024 + 4 * t) = z;
        if (blockIdx.x == 0 && t < 128) ws[WS_L + t] = 0.f;
    }

    // qfull slice: j = t&63, quarter q = t>>6 sums 128 c's
    {
        int j = t & 63, q = t >> 6;
        const float* wq = Wq + h * 64 + j;
        float p = 0.f;
#pragma unroll 16
        for (int c = q * 128; c < q * 128 + 128; ++c)
            p = fmaf(cls[c], wq[(size_t)c * C_], p);
        red[t] = p;
    }
    __syncthreads();
    if (t < 64) qf[t] = (red[t] + red[t + 64] + red[t + 128] + red[t + 192]) * 0.125f;
    __syncthreads();

    // qk tile: 4 threads per column, each sums 16 d's (4x float4)
    {
        int cl = t & 63, q = t >> 6;
        int c = cc * 64 + cl;
        const float4* wk = (const float4*)(Wk + (size_t)c * C_ + h * 64 + q * 16);
        const float4* qv = (const float4*)(qf + q * 16);
        float p = 0.f;
#pragma unroll
        for (int u = 0; u < 4; ++u) {
            float4 w4 = wk[u], q4 = qv[u];
            p = fmaf(w4.x, q4.x, p); p = fmaf(w4.y, q4.y, p);
            p = fmaf(w4.z, q4.z, p); p = fmaf(w4.w, q4.w, p);
        }
        red[t] = p;
    }
    __syncthreads();
    if (t < 64)
        ws[WS_QK + h * C_ + cc * 64 + t] = red[t] + red[t + 64] + red[t + 128] + red[t + 192];
}

// ---------------- K2: main streaming pass (DMA-FIFO + atomic epilogue) ----------------
__global__ __launch_bounds__(256) void k_main(const float* __restrict__ x,
                                              float* __restrict__ ws, int CH) {
    __shared__ float smem[4][2][1024];   // wave-private [w][buf][2 rows]; 32 KB
    __shared__ float sl[8];

    int blk = blockIdx.x;
    int b = blk / CH, chunk = blk % CH;
    int lane = threadIdx.x & 63, wave = threadIdx.x >> 6;
    int rpb = N_ / CH;            // 256
    int n0 = chunk * rpb;
    const float* xp = x + ((size_t)b * N_ + n0) * C_;
    const float* gw = xp + (size_t)(2 * wave) * C_;

    const float* qk = ws + WS_QK;
    int lo = 4 * lane, hi = 256 + 4 * lane;
    float qr[8][8];
#pragma unroll
    for (int h = 0; h < 8; ++h) {
        float4 a = *(const float4*)(qk + h * C_ + lo);
        float4 bb = *(const float4*)(qk + h * C_ + hi);
        qr[h][0] = a.x;  qr[h][1] = a.y;  qr[h][2] = a.z;  qr[h][3] = a.w;
        qr[h][4] = bb.x; qr[h][5] = bb.y; qr[h][6] = bb.z; qr[h][7] = bb.w;
    }

    float acc[8][8];
#pragma unroll
    for (int h = 0; h < 8; ++h)
#pragma unroll
        for (int j = 0; j < 8; ++j) acc[h][j] = 0.f;
    float lsum = 0.f;

    auto row_body = [&](const float4& v0, const float4& v1) {
        float xv[8] = {v0.x, v0.y, v0.z, v0.w, v1.x, v1.y, v1.z, v1.w};
        float p[8];
#pragma unroll
        for (int h = 0; h < 8; ++h) {
            float s = xv[0] * qr[h][0];
#pragma unroll
            for (int j = 1; j < 8; ++j) s = fmaf(xv[j], qr[h][j], s);
            p[h] = s;
        }
        int b0 = lane & 1, b1 = lane & 2, b2 = lane & 4;
        float t4[4];
#pragma unroll
        for (int i = 0; i < 4; ++i) {
            float send = b0 ? p[i] : p[i + 4];
            float recv = __shfl_xor(send, 1, 64);
            t4[i] = (b0 ? p[i + 4] : p[i]) + recv;
        }
        float u2[2];
#pragma unroll
        for (int i = 0; i < 2; ++i) {
            float send = b1 ? t4[i] : t4[i + 2];
            float recv = __shfl_xor(send, 2, 64);
            u2[i] = (b1 ? t4[i + 2] : t4[i]) + recv;
        }
        float send = b2 ? u2[0] : u2[1];
        float recv = __shfl_xor(send, 4, 64);
        float v = (b2 ? u2[1] : u2[0]) + recv;
        v += __shfl_xor(v, 8, 64);
        v += __shfl_xor(v, 16, 64);
        v += __shfl_xor(v, 32, 64);
        float e = __expf(v);   // logits ~N(0,0.2): un-normalized softmax safe
        lsum += e;
#pragma unroll
        for (int h = 0; h < 8; ++h) {
            int src = ((h & 4) >> 2) | (h & 2) | ((h & 1) << 2);
            float wf = __int_as_float(__builtin_amdgcn_readlane(__float_as_int(e), src));
#pragma unroll
            for (int j = 0; j < 8; ++j) acc[h][j] = fmaf(wf, xv[j], acc[h][j]);
        }
    };

    float* Lb[2] = {&smem[wave][0][0], &smem[wave][1][0]};
#pragma unroll
    for (int k = 0; k < 4; ++k)
        dma16(gw + k * 256 + lo, Lb[0] + k * 256);

#pragma unroll 1
    for (int T = 0; T < NT_; ++T) {
        float* cur = Lb[T & 1];
        float* nxt = Lb[(T & 1) ^ 1];
        if (T + 1 < NT_) {
            const float* gn = gw + (size_t)(T + 1) * 8 * C_;
#pragma unroll
            for (int k = 0; k < 4; ++k)
                dma16(gn + k * 256 + lo, nxt + k * 256);
            asm volatile("s_waitcnt vmcnt(4)" ::: "memory");
        } else {
            asm volatile("s_waitcnt vmcnt(0)" ::: "memory");
        }
#pragma unroll
        for (int r = 0; r < 2; ++r) {
            float4 v0 = *(const float4*)(cur + r * 512 + lo);
            float4 v1 = *(const float4*)(cur + r * 512 + hi);
            row_body(v0, v1);
        }
    }

    float lw[8];
#pragma unroll
    for (int h = 0; h < 8; ++h) {
        int src = ((h & 4) >> 2) | (h & 2) | ((h & 1) << 2);
        lw[h] = __int_as_float(__builtin_amdgcn_readlane(__float_as_int(lsum), src));
    }

    __syncthreads();
    float* sacc = &smem[0][0][0];   // 8*512 floats
    for (int w = 0; w < 4; ++w) {
        if (wave == w) {
#pragma unroll
            for (int h = 0; h < 8; ++h) {
                float4 vlo = {acc[h][0], acc[h][1], acc[h][2], acc[h][3]};
                float4 vhi = {acc[h][4], acc[h][5], acc[h][6], acc[h][7]};
                float4* d0 = (float4*)&sacc[h * C_ + lo];
                float4* d1 = (float4*)&sacc[h * C_ + hi];
                if (w == 0) { d0[0] = vlo; d1[0] = vhi; }
                else {
                    float4 a0 = d0[0], a1 = d1[0];
                    a0.x += vlo.x; a0.y += vlo.y; a0.z += vlo.z; a0.w += vlo.w;
                    a1.x += vhi.x; a1.y += vhi.y; a1.z += vhi.z; a1.w += vhi.w;
                    d0[0] = a0; d1[0] = a1;
                }
            }
            if (lane == 0) {
#pragma unroll
                for (int h = 0; h < 8; ++h) {
                    if (w == 0) sl[h] = lw[h]; else sl[h] += lw[h];
                }
            }
        }
        __syncthreads();
    }

    // fire-and-forget atomic accumulate into global aa / l (replaces partials)
    float* aa = ws + WS_AA + b * 4096;
#pragma unroll 16
    for (int k = threadIdx.x; k < 4096; k += 256)
        atomicAdd(&aa[k], sacc[k]);
    if (threadIdx.x < 8)
        atomicAdd(&ws[WS_L + b * 8 + threadIdx.x], sl[threadIdx.x]);
}

// ---------------- K3: pooled (c-split halves) = (1/l) * aa @ Wv ----------------
__global__ void k_proj1(const float* __restrict__ ws, const float* __restrict__ Wv,
                        float* __restrict__ pp) {
    int gid = blockIdx.x * 256 + threadIdx.x;  // [0, 16384)
    int half = gid >> 13;
    int r = gid & 8191;
    int b = r >> 9, o = r & 511, h = o >> 6;
    const float* aa = ws + WS_AA + b * 4096 + h * C_;
    float Li = 1.f / ws[WS_L + b * 8 + h];
    int c0 = half * 256;
    float s = 0.f;
#pragma unroll 16
    for (int c = 0; c < 256; ++c)
        s = fmaf(aa[c0 + c], Wv[(size_t)(c0 + c) * C_ + o], s);
    pp[half * 8192 + r] = s * Li;
}

// ---------------- K4: out = pooled @ Wp + bp ----------------
__global__ void k_proj2(const float* __restrict__ ws, const float* __restrict__ Wp,
                        const float* __restrict__ bp, float* __restrict__ out) {
    int gid = blockIdx.x * 256 + threadIdx.x;  // [0, 8192)
    int b = gid >> 9, o = gid & 511;
    const float* pp = ws + WS_PP + b * 512;
    float s = bp[o];
#pragma unroll 16
    for (int c = 0; c < 512; ++c) {
        float pc = pp[c] + pp[8192 + c];
        s = fmaf(pc, Wp[(size_t)c * C_ + o], s);
    }
    out[(size_t)b * C_ + o] = s;
}

extern "C" void kernel_launch(void* const* d_in, const int* in_sizes, int n_in,
                              void* d_out, int out_size, void* d_ws, size_t ws_size,
                              hipStream_t stream) {
    const float* x   = (const float*)d_in[0];
    const float* cls = (const float*)d_in[1];
    const float* Wq  = (const float*)d_in[2];
    const float* Wk  = (const float*)d_in[3];
    const float* Wv  = (const float*)d_in[4];
    const float* Wp  = (const float*)d_in[5];
    const float* bp  = (const float*)d_in[6];
    float* out = (float*)d_out;
    float* ws  = (float*)d_ws;

    k_prep<<<64, 256, 0, stream>>>(cls, Wq, Wk, ws);
    k_main<<<B_ * CH_, 256, 0, stream>>>(x, ws, CH_);
    k_proj1<<<64, 256, 0, stream>>>(ws, Wv, ws + WS_PP);
    k_proj2<<<32, 256, 0, stream>>>(ws, Wp, bp, out);
}

// Round 13
// 104.209 us; speedup vs baseline: 4.3383x; 1.0051x over previous
//
#include <hip/hip_runtime.h>
#include <hip/hip_bf16.h>

#define B_ 16
#define N_ 8192
#define C_ 512
#define H_ 8
#define CH_ 32
#define NT_ 32   // tiles per block (256 rows / 8 rows-per-tile)

// ws float layout:
//   [512, 4608)       qk[h][c]  (8 x 512)
//   [4608, 4736)      l[b][h] atomic sums (16 x 8)
//   [4736, 70272)     aa[b][h][c] atomic-accumulated weighted sums (16 x 8 x 512)
//   [70272, 86656)    pp[half][b][o] partial pooled (2 x 16 x 512)
#define WS_QK   512
#define WS_L    4608
#define WS_AA   4736
#define WS_PP   70272

// k_main history: consumption capped ~4.1TB/s (R8 probe). Occupancy (R10),
// register prefetch depth (R3/R7), DMA depth-1 (R11/R12) all run at the cap.
// R13 theory: depth-1 FIFO stalls ~200-900cy per tile (compute 680cy < HBM
// 900cy, only 2 waves/SIMD). Fix: 4-buffer FIFO, 3 tiles in flight, vmcnt(12).

#if defined(__has_builtin)
#if __has_builtin(__builtin_amdgcn_global_load_lds)
#define HAVE_GLD 1
#endif
#endif

#ifdef HAVE_GLD
__device__ __forceinline__ void dma16(const float* g, float* l) {
    __builtin_amdgcn_global_load_lds(
        (const __attribute__((address_space(1))) unsigned int*)g,
        (__attribute__((address_space(3))) unsigned int*)l, 16, 0, 0);
}
#else
__device__ __forceinline__ void dma16(const float* g, float* l) {
    *(float4*)(l + 4 * (threadIdx.x & 63)) = *(const float4*)g;
}
#endif

// ---------------- K1: fused prep ----------------
__global__ void k_prep(const float* __restrict__ cls, const float* __restrict__ Wq,
                       const float* __restrict__ Wk, float* __restrict__ ws) {
    __shared__ float red[256];
    __shared__ float qf[64];
    int t = threadIdx.x;
    int h = blockIdx.x >> 3, cc = blockIdx.x & 7;

    {
        float4 z = {0.f, 0.f, 0.f, 0.f};
        *(float4*)(ws + WS_AA + blockIdx.x * 1024 + 4 * t) = z;
        if (blockIdx.x == 0 && t < 128) ws[WS_L + t] = 0.f;
    }

    {
        int j = t & 63, q = t >> 6;
        const float* wq = Wq + h * 64 + j;
        float p = 0.f;
#pragma unroll 16
        for (int c = q * 128; c < q * 128 + 128; ++c)
            p = fmaf(cls[c], wq[(size_t)c * C_], p);
        red[t] = p;
    }
    __syncthreads();
    if (t < 64) qf[t] = (red[t] + red[t + 64] + red[t + 128] + red[t + 192]) * 0.125f;
    __syncthreads();

    {
        int cl = t & 63, q = t >> 6;
        int c = cc * 64 + cl;
        const float4* wk = (const float4*)(Wk + (size_t)c * C_ + h * 64 + q * 16);
        const float4* qv = (const float4*)(qf + q * 16);
        float p = 0.f;
#pragma unroll
        for (int u = 0; u < 4; ++u) {
            float4 w4 = wk[u], q4 = qv[u];
            p = fmaf(w4.x, q4.x, p); p = fmaf(w4.y, q4.y, p);
            p = fmaf(w4.z, q4.z, p); p = fmaf(w4.w, q4.w, p);
        }
        red[t] = p;
    }
    __syncthreads();
    if (t < 64)
        ws[WS_QK + h * C_ + cc * 64 + t] = red[t] + red[t + 64] + red[t + 128] + red[t + 192];
}

// ---------------- K2: main streaming pass (depth-3 DMA FIFO) ----------------
__global__ __launch_bounds__(256) void k_main(const float* __restrict__ x,
                                              float* __restrict__ ws, int CH) {
    __shared__ float smem[4][4][1024];   // [wave][buf][2 rows]; 64 KB
    __shared__ float sl[8];

    int blk = blockIdx.x;
    int b = blk / CH, chunk = blk % CH;
    int lane = threadIdx.x & 63, wave = threadIdx.x >> 6;
    int rpb = N_ / CH;            // 256
    int n0 = chunk * rpb;
    const float* xp = x + ((size_t)b * N_ + n0) * C_;
    const float* gw = xp + (size_t)(2 * wave) * C_;   // wave's rows in tile 0

    const float* qk = ws + WS_QK;
    int lo = 4 * lane, hi = 256 + 4 * lane;
    float qr[8][8];
#pragma unroll
    for (int h = 0; h < 8; ++h) {
        float4 a = *(const float4*)(qk + h * C_ + lo);
        float4 bb = *(const float4*)(qk + h * C_ + hi);
        qr[h][0] = a.x;  qr[h][1] = a.y;  qr[h][2] = a.z;  qr[h][3] = a.w;
        qr[h][4] = bb.x; qr[h][5] = bb.y; qr[h][6] = bb.z; qr[h][7] = bb.w;
    }

    float acc[8][8];
#pragma unroll
    for (int h = 0; h < 8; ++h)
#pragma unroll
        for (int j = 0; j < 8; ++j) acc[h][j] = 0.f;
    float lsum = 0.f;

    auto row_body = [&](const float4& v0, const float4& v1) {
        float xv[8] = {v0.x, v0.y, v0.z, v0.w, v1.x, v1.y, v1.z, v1.w};
        float p[8];
#pragma unroll
        for (int h = 0; h < 8; ++h) {
            float s = xv[0] * qr[h][0];
#pragma unroll
            for (int j = 1; j < 8; ++j) s = fmaf(xv[j], qr[h][j], s);
            p[h] = s;
        }
        int b0 = lane & 1, b1 = lane & 2, b2 = lane & 4;
        float t4[4];
#pragma unroll
        for (int i = 0; i < 4; ++i) {
            float send = b0 ? p[i] : p[i + 4];
            float recv = __shfl_xor(send, 1, 64);
            t4[i] = (b0 ? p[i + 4] : p[i]) + recv;
        }
        float u2[2];
#pragma unroll
        for (int i = 0; i < 2; ++i) {
            float send = b1 ? t4[i] : t4[i + 2];
            float recv = __shfl_xor(send, 2, 64);
            u2[i] = (b1 ? t4[i + 2] : t4[i]) + recv;
        }
        float send = b2 ? u2[0] : u2[1];
        float recv = __shfl_xor(send, 4, 64);
        float v = (b2 ? u2[1] : u2[0]) + recv;
        v += __shfl_xor(v, 8, 64);
        v += __shfl_xor(v, 16, 64);
        v += __shfl_xor(v, 32, 64);
        float e = __expf(v);   // logits ~N(0,0.2): un-normalized softmax safe
        lsum += e;
#pragma unroll
        for (int h = 0; h < 8; ++h) {
            int src = ((h & 4) >> 2) | (h & 2) | ((h & 1) << 2);
            float wf = __int_as_float(__builtin_amdgcn_readlane(__float_as_int(e), src));
#pragma unroll
            for (int j = 0; j < 8; ++j) acc[h][j] = fmaf(wf, xv[j], acc[h][j]);
        }
    };

    // prologue: stage tiles 0,1,2 (12 outstanding DMAs)
#pragma unroll
    for (int T = 0; T < 3; ++T) {
        const float* g = gw + (size_t)T * 8 * C_;
        float* d = &smem[wave][T][0];
#pragma unroll
        for (int k = 0; k < 4; ++k)
            dma16(g + k * 256 + lo, d + k * 256);
    }

#pragma unroll 1
    for (int T = 0; T < NT_; ++T) {
        // issue tile T+3 (clamped to last tile; lands in a consumed buffer)
        {
            int tn = T + 3 < NT_ ? T + 3 : NT_ - 1;
            const float* g = gw + (size_t)tn * 8 * C_;
            float* d = &smem[wave][(T + 3) & 3][0];
#pragma unroll
            for (int k = 0; k < 4; ++k)
                dma16(g + k * 256 + lo, d + k * 256);
        }
        asm volatile("s_waitcnt vmcnt(12)" ::: "memory");  // tile T landed
        float* cur = &smem[wave][T & 3][0];
#pragma unroll
        for (int r = 0; r < 2; ++r) {
            float4 v0 = *(const float4*)(cur + r * 512 + lo);
            float4 v1 = *(const float4*)(cur + r * 512 + hi);
            row_body(v0, v1);
        }
    }
    asm volatile("s_waitcnt vmcnt(0)" ::: "memory");  // drain dummy tail DMAs

    float lw[8];
#pragma unroll
    for (int h = 0; h < 8; ++h) {
        int src = ((h & 4) >> 2) | (h & 2) | ((h & 1) << 2);
        lw[h] = __int_as_float(__builtin_amdgcn_readlane(__float_as_int(lsum), src));
    }

    __syncthreads();
    float* sacc = &smem[0][0][0];   // 8*512 floats (reuse)
    for (int w = 0; w < 4; ++w) {
        if (wave == w) {
#pragma unroll
            for (int h = 0; h < 8; ++h) {
                float4 vlo = {acc[h][0], acc[h][1], acc[h][2], acc[h][3]};
                float4 vhi = {acc[h][4], acc[h][5], acc[h][6], acc[h][7]};
                float4* d0 = (float4*)&sacc[h * C_ + lo];
                float4* d1 = (float4*)&sacc[h * C_ + hi];
                if (w == 0) { d0[0] = vlo; d1[0] = vhi; }
                else {
                    float4 a0 = d0[0], a1 = d1[0];
                    a0.x += vlo.x; a0.y += vlo.y; a0.z += vlo.z; a0.w += vlo.w;
                    a1.x += vhi.x; a1.y += vhi.y; a1.z += vhi.z; a1.w += vhi.w;
                    d0[0] = a0; d1[0] = a1;
                }
            }
            if (lane == 0) {
#pragma unroll
                for (int h = 0; h < 8; ++h) {
                    if (w == 0) sl[h] = lw[h]; else sl[h] += lw[h];
                }
            }
        }
        __syncthreads();
    }

    float* aa = ws + WS_AA + b * 4096;
#pragma unroll 16
    for (int k = threadIdx.x; k < 4096; k += 256)
        atomicAdd(&aa[k], sacc[k]);
    if (threadIdx.x < 8)
        atomicAdd(&ws[WS_L + b * 8 + threadIdx.x], sl[threadIdx.x]);
}

// ---------------- K3: pooled (c-split halves) = (1/l) * aa @ Wv ----------------
__global__ void k_proj1(const float* __restrict__ ws, const float* __restrict__ Wv,
                        float* __restrict__ pp) {
    int gid = blockIdx.x * 256 + threadIdx.x;  // [0, 16384)
    int half = gid >> 13;
    int r = gid & 8191;
    int b = r >> 9, o = r & 511, h = o >> 6;
    const float* aa = ws + WS_AA + b * 4096 + h * C_;
    float Li = 1.f / ws[WS_L + b * 8 + h];
    int c0 = half * 256;
    float s = 0.f;
#pragma unroll 16
    for (int c = 0; c < 256; ++c)
        s = fmaf(aa[c0 + c], Wv[(size_t)(c0 + c) * C_ + o], s);
    pp[half * 8192 + r] = s * Li;
}

// ---------------- K4: out = pooled @ Wp + bp ----------------
__global__ void k_proj2(const float* __restrict__ ws, const float* __restrict__ Wp,
                        const float* __restrict__ bp, float* __restrict__ out) {
    int gid = blockIdx.x * 256 + threadIdx.x;  // [0, 8192)
    int b = gid >> 9, o = gid & 511;
    const float* pp = ws + WS_PP + b * 512;
    float s = bp[o];
#pragma unroll 16
    for (int c = 0; c < 512; ++c) {
        float pc = pp[c] + pp[8192 + c];
        s = fmaf(pc, Wp[(size_t)c * C_ + o], s);
    }
    out[(size_t)b * C_ + o] = s;
}

extern "C" void kernel_launch(void* const* d_in, const int* in_sizes, int n_in,
                              void* d_out, int out_size, void* d_ws, size_t ws_size,
                              hipStream_t stream) {
    const float* x   = (const float*)d_in[0];
    const float* cls = (const float*)d_in[1];
    const float* Wq  = (const float*)d_in[2];
    const float* Wk  = (const float*)d_in[3];
    const float* Wv  = (const float*)d_in[4];
    const float* Wp  = (const float*)d_in[5];
    const float* bp  = (const float*)d_in[6];
    float* out = (float*)d_out;
    float* ws  = (float*)d_ws;

    k_prep<<<64, 256, 0, stream>>>(cls, Wq, Wk, ws);
    k_main<<<B_ * CH_, 256, 0, stream>>>(x, ws, CH_);
    k_proj1<<<64, 256, 0, stream>>>(ws, Wv, ws + WS_PP);
    k_proj2<<<32, 256, 0, stream>>>(ws, Wp, bp, out);
}